// Round 10
// baseline (416.441 us; speedup 1.0000x reference)
//
#include <hip/hip_runtime.h>
#include <hip/hip_bf16.h>

#define NN     8192
#define NFEAT  512
#define NHID   128
#define NCLASS 40
#define NLAY   3
#define CAPA   128           // CSR capacity/row (nnz ~ Binomial(8192,0.002), mean 16.4)
#define FSZ    ((size_t)NN * NHID)

typedef float f32x4 __attribute__((ext_vector_type(4)));

// ================================================================ D1: fc1 + adjA scan + setup
// grid (384 + NN + 1). bx<384: fc1 tile. 384<=bx<384+NN: scan adjA row (batched v[8]). last: setup.
// LDS 12.8KB, lb(256,8) -> 8 blocks/CU (fc1 fits 48 VGPR per R7 measurement).
__global__ __launch_bounds__(256, 8) void k_d1(
    const float* __restrict__ x, const float* __restrict__ fc1w, const float* __restrict__ fc1b,
    const float* __restrict__ adjA, const float* __restrict__ hop, const float* __restrict__ w,
    float* __restrict__ tmps, float* __restrict__ f_mask, float* __restrict__ f_watt,
    float* __restrict__ colsum, float* __restrict__ rowsumA,
    int* __restrict__ cntsA, int* __restrict__ colsA, float* __restrict__ valsA)
{
    __shared__ float smem[3200];       // fc1: As[16][68] | Bs[16][132]; scan: [0]=lcnt [1]=lsum
    const int bx = blockIdx.x, tid = threadIdx.x;

    if (bx < 384) {
        // ---------------- fc1 tile: BM=64, BN=128, BK=16 ----------------
        float* As = smem;              // [16][68]
        float* Bs = smem + 1088;       // [16][132]
        const int tx = tid & 15, ty = tid >> 4;
        const int bm = (bx & 127) * 64;
        const int layer = bx >> 7;
        const int bn = layer * 128;
        float acc[4][8] = {};

        const int rA = tid >> 2, cA = (tid & 3) * 4;
        for (int kt = 0; kt < NFEAT; kt += 16) {
            f32x4 va = *reinterpret_cast<const f32x4*>(&x[(size_t)(bm + rA) * NFEAT + kt + cA]);
            As[(cA + 0) * 68 + rA] = va[0];
            As[(cA + 1) * 68 + rA] = va[1];
            As[(cA + 2) * 68 + rA] = va[2];
            As[(cA + 3) * 68 + rA] = va[3];
            #pragma unroll
            for (int it = 0; it < 2; ++it) {
                int L = tid + it * 256;
                int r = L >> 2, c4 = (L & 3) * 4;
                f32x4 vb = *reinterpret_cast<const f32x4*>(&fc1w[(size_t)(bn + r) * NFEAT + kt + c4]);
                Bs[(c4 + 0) * 132 + r] = vb[0];
                Bs[(c4 + 1) * 132 + r] = vb[1];
                Bs[(c4 + 2) * 132 + r] = vb[2];
                Bs[(c4 + 3) * 132 + r] = vb[3];
            }
            __syncthreads();
            #pragma unroll
            for (int kk = 0; kk < 16; ++kk) {
                f32x4 ra  = *reinterpret_cast<const f32x4*>(&As[kk * 68 + ty * 4]);
                f32x4 rb0 = *reinterpret_cast<const f32x4*>(&Bs[kk * 132 + tx * 4]);
                f32x4 rb1 = *reinterpret_cast<const f32x4*>(&Bs[kk * 132 + tx * 4 + 64]);
                #pragma unroll
                for (int i = 0; i < 4; ++i) {
                    #pragma unroll
                    for (int j = 0; j < 4; ++j) {
                        acc[i][j]     = fmaf(ra[i], rb0[j], acc[i][j]);
                        acc[i][j + 4] = fmaf(ra[i], rb1[j], acc[i][j + 4]);
                    }
                }
            }
            __syncthreads();
        }
        const float* bofs = fc1b + bn;
        #pragma unroll
        for (int i = 0; i < 4; ++i) {
            int m = bm + ty * 4 + i;
            #pragma unroll
            for (int j = 0; j < 8; ++j) {
                int lc = (j < 4) ? (tx * 4 + j) : (64 + tx * 4 + (j - 4));
                tmps[(size_t)layer * FSZ + (size_t)m * NHID + lc] = acc[i][j] + bofs[lc];
            }
        }
    } else if (bx < 384 + NN) {
        // ---------------- adjA scan (one row, batched loads) ----------------
        const int row = bx - 384;
        int* s_lcnt = (int*)smem;
        float* s_lsum = smem + 1;
        if (tid == 0) { *s_lcnt = 0; *s_lsum = 0.f; }
        __syncthreads();
        const f32x4* arow = reinterpret_cast<const f32x4*>(adjA + (size_t)row * NN);
        int* rc = colsA + (size_t)row * CAPA;
        float* rv = valsA + (size_t)row * CAPA;

        f32x4 v[8];
        #pragma unroll
        for (int i = 0; i < 8; ++i) v[i] = arow[tid + (i << 8)];

        float ls = 0.f;
        #pragma unroll
        for (int i = 0; i < 8; ++i) {
            const int c4 = tid + (i << 8);
            #pragma unroll
            for (int k = 0; k < 4; ++k) {
                if (v[i][k] > 0.f) {
                    int p = atomicAdd(s_lcnt, 1);
                    if (p < CAPA) { rc[p] = c4 * 4 + k; rv[p] = v[i][k]; }
                    ls += v[i][k];
                }
            }
        }
        if (ls != 0.f) atomicAdd(s_lsum, ls);
        __syncthreads();
        if (tid == 0) {
            int n = *s_lcnt;
            cntsA[row] = n < CAPA ? n : CAPA;
            rowsumA[row] = *s_lsum;
        }
    } else {
        // ---------------- setup ----------------
        colsum[tid] = 0.f;             // 256 entries (2 layers x 128)
        if (tid == 0) {
            float m = fmaxf(fmaxf(hop[0], hop[1]), hop[2]);
            float e0 = expf(hop[0] - m), e1 = expf(hop[1] - m), e2 = expf(hop[2] - m);
            float s = e0 + e1 + e2;
            f_mask[0] = e0 / s; f_mask[1] = e1 / s; f_mask[2] = e2 / s;
            for (int l = 0; l < 2; ++l) {
                float a = w[2 * l], b = w[2 * l + 1];
                float mm = fmaxf(a, b);
                float ea = expf(a - mm), eb = expf(b - mm);
                float ss = ea + eb;
                f_watt[2 * l] = ea / ss; f_watt[2 * l + 1] = eb / ss;
            }
        }
    }
}

// ================================================================ D2: spmm1 (both layers) + colsum + adj1 scan
// grid (NN + 64 + NN). bx<NN: spmm row (both layers, 256 thr). bx<NN+64: colsum chunk. else: scan adj1 row.
__global__ __launch_bounds__(256, 8) void k_d2(
    const int* __restrict__ cntsA, const int* __restrict__ colsA, const float* __restrict__ valsA,
    const float* __restrict__ tmps, float* __restrict__ tmp_att, float* __restrict__ colsum,
    const float* __restrict__ adj1,
    int* __restrict__ cnts12, int* __restrict__ cols12, float* __restrict__ vals12)
{
    __shared__ int sc[CAPA];
    __shared__ float sv[CAPA];
    __shared__ int s_lcnt;
    const int bx = blockIdx.x, t = threadIdx.x;

    if (bx < NN) {
        // ---------------- spmm both layers of row bx ----------------
        const int row = bx;
        const int n = cntsA[row];
        for (int p = t; p < n; p += 256) { sc[p] = colsA[(size_t)row * CAPA + p]; sv[p] = valsA[(size_t)row * CAPA + p]; }
        __syncthreads();
        const int h = t >> 7, col = t & 127;
        const float* X = tmps + (size_t)(h + 1) * FSZ;
        float a0 = 0.f, a1 = 0.f, a2 = 0.f, a3 = 0.f;
        int p = 0;
        for (; p + 4 <= n; p += 4) {
            a0 = fmaf(sv[p],     X[(size_t)sc[p]     * NHID + col], a0);
            a1 = fmaf(sv[p + 1], X[(size_t)sc[p + 1] * NHID + col], a1);
            a2 = fmaf(sv[p + 2], X[(size_t)sc[p + 2] * NHID + col], a2);
            a3 = fmaf(sv[p + 3], X[(size_t)sc[p + 3] * NHID + col], a3);
        }
        for (; p < n; ++p) a0 = fmaf(sv[p], X[(size_t)sc[p] * NHID + col], a0);
        tmp_att[(size_t)h * FSZ + (size_t)row * NHID + col] = (a0 + a1) + (a2 + a3);
    } else if (bx < NN + 64) {
        // ---------------- colsum chunk ----------------
        const int c = bx - NN;
        const int h = t >> 7, col = t & 127;
        const float* X = tmps + (size_t)(h + 1) * FSZ + (size_t)c * 128 * NHID;
        float a = 0.f;
        for (int r = 0; r < 128; ++r) a += X[(size_t)r * NHID + col];
        atomicAdd(&colsum[h * NHID + col], a);
    } else {
        // ---------------- adj1 scan (mat 0) ----------------
        const int row = bx - NN - 64;
        if (t == 0) s_lcnt = 0;
        __syncthreads();
        const f32x4* arow = reinterpret_cast<const f32x4*>(adj1 + (size_t)row * NN);
        int* rc = cols12 + (size_t)row * CAPA;
        float* rv = vals12 + (size_t)row * CAPA;

        f32x4 v[8];
        #pragma unroll
        for (int i = 0; i < 8; ++i) v[i] = arow[t + (i << 8)];

        #pragma unroll
        for (int i = 0; i < 8; ++i) {
            const int c4 = t + (i << 8);
            #pragma unroll
            for (int k = 0; k < 4; ++k) {
                if (v[i][k] > 0.f) {
                    int p = atomicAdd(&s_lcnt, 1);
                    if (p < CAPA) { rc[p] = c4 * 4 + k; rv[p] = v[i][k]; }
                }
            }
        }
        __syncthreads();
        if (t == 0) cnts12[row] = s_lcnt < CAPA ? s_lcnt : CAPA;
    }
}

// ================================================================ D3: t2qkm + adj2 scan
// grid (256 + NN). b<256: T2 gather + QKm GEMM. else: scan adj2 row (mat 1).
__global__ __launch_bounds__(256, 4) void k_d3(
    const int* __restrict__ cntsA, const int* __restrict__ colsA, const float* __restrict__ valsA,
    const float* __restrict__ tmp_att, const float* __restrict__ Qw, const float* __restrict__ Kw,
    const float* __restrict__ Qb, const float* __restrict__ Kb,
    const float* __restrict__ rowsumA, float* __restrict__ QKm,
    const float* __restrict__ adj2,
    int* __restrict__ cnts12, int* __restrict__ cols12, float* __restrict__ vals12)
{
    __shared__ float AsT[8192];        // t2: [k=128][row=64]; scan: [0]=lcnt
    const int b = blockIdx.x, tid = threadIdx.x;

    if (b < 256) {
        // ---------------- T2 gather + QKm GEMM ----------------
        const int bm = (b & 127) * 64, Lz = b >> 7;
        const float* X = tmp_att + (size_t)Lz * FSZ;
        {
            const int lrow = tid >> 2, coff = (tid & 3) * 32;
            const int row = bm + lrow;
            f32x4 acc[8] = {};
            const int n = cntsA[row];
            const int* rc = colsA + (size_t)row * CAPA;
            const float* rv = valsA + (size_t)row * CAPA;
            for (int p = 0; p < n; ++p) {
                int c = rc[p];
                float v = rv[p];
                const f32x4* src = reinterpret_cast<const f32x4*>(X + (size_t)c * NHID + coff);
                #pragma unroll
                for (int j = 0; j < 8; ++j) {
                    f32x4 s = src[j];
                    acc[j][0] = fmaf(v, s[0], acc[j][0]);
                    acc[j][1] = fmaf(v, s[1], acc[j][1]);
                    acc[j][2] = fmaf(v, s[2], acc[j][2]);
                    acc[j][3] = fmaf(v, s[3], acc[j][3]);
                }
            }
            #pragma unroll
            for (int j = 0; j < 8; ++j)
                #pragma unroll
                for (int q = 0; q < 4; ++q)
                    AsT[(coff + j * 4 + q) * 64 + lrow] = acc[j][q];
        }
        __syncthreads();

        const int tx = tid & 15, ty = tid >> 4;
        float rs[4];
        #pragma unroll
        for (int i = 0; i < 4; ++i) rs[i] = rowsumA[bm + ty * 4 + i];
        float* C = QKm + (size_t)Lz * NN * 256;

        #pragma unroll
        for (int ch = 0; ch < 4; ++ch) {
            const int bn = ch * 64;
            const float* Bp; const float* bp; int bc;
            if (bn < 128) { Bp = Qw + (size_t)Lz * NHID * NHID; bp = Qb + (size_t)Lz * NHID; bc = bn; }
            else          { Bp = Kw + (size_t)Lz * NHID * NHID; bp = Kb + (size_t)Lz * NHID; bc = bn - 128; }
            float acc[4][4] = {};
            for (int k4 = 0; k4 < NHID; k4 += 4) {
                f32x4 wv[4];
                #pragma unroll
                for (int j = 0; j < 4; ++j)
                    wv[j] = *reinterpret_cast<const f32x4*>(&Bp[(size_t)(bc + tx * 4 + j) * NHID + k4]);
                #pragma unroll
                for (int q = 0; q < 4; ++q) {
                    f32x4 ra = *reinterpret_cast<const f32x4*>(&AsT[(k4 + q) * 64 + ty * 4]);
                    #pragma unroll
                    for (int i = 0; i < 4; ++i)
                        #pragma unroll
                        for (int j = 0; j < 4; ++j)
                            acc[i][j] = fmaf(ra[i], wv[j][q], acc[i][j]);
                }
            }
            #pragma unroll
            for (int i = 0; i < 4; ++i) {
                int m = bm + ty * 4 + i;
                #pragma unroll
                for (int j = 0; j < 4; ++j) {
                    int nc = bn + tx * 4 + j;
                    C[(size_t)m * 256 + nc] = acc[i][j] + rs[i] * bp[bc + tx * 4 + j];
                }
            }
        }
    } else {
        // ---------------- adj2 scan (mat 1) ----------------
        const int row = b - 256;
        int* s_lcnt = (int*)AsT;
        if (tid == 0) *s_lcnt = 0;
        __syncthreads();
        const f32x4* arow = reinterpret_cast<const f32x4*>(adj2 + (size_t)row * NN);
        int* rc = cols12 + (size_t)(NN + row) * CAPA;
        float* rv = vals12 + (size_t)(NN + row) * CAPA;

        f32x4 v[8];
        #pragma unroll
        for (int i = 0; i < 8; ++i) v[i] = arow[tid + (i << 8)];

        #pragma unroll
        for (int i = 0; i < 8; ++i) {
            const int c4 = tid + (i << 8);
            #pragma unroll
            for (int k = 0; k < 4; ++k) {
                if (v[i][k] > 0.f) {
                    int p = atomicAdd(s_lcnt, 1);
                    if (p < CAPA) { rc[p] = c4 * 4 + k; rv[p] = v[i][k]; }
                }
            }
        }
        __syncthreads();
        if (tid == 0) cnts12[NN + row] = *s_lcnt < CAPA ? *s_lcnt : CAPA;
    }
}

// ================================================================ D4: attention (both layers) + clf
__global__ __launch_bounds__(256) void k_attn_clf(
    const int* __restrict__ cnts12, const int* __restrict__ cols12, const float* __restrict__ vals12,
    const float* __restrict__ QKm, const float* __restrict__ tmps,
    const float* __restrict__ colsum, const float* __restrict__ watt,
    const float* __restrict__ mask, const float* __restrict__ Wc, const float* __restrict__ bc,
    float* __restrict__ out)
{
    const int row = blockIdx.x, t = threadIdx.x;
    const int h = t >> 7, ht = t & 127;          // half h: layer h+1
    __shared__ int cols[2][CAPA];
    __shared__ float avals[2][CAPA];
    __shared__ float svals[2][CAPA];
    __shared__ __align__(16) float qrow[2][NHID];
    __shared__ float ws[4];
    __shared__ float ws0[2];
    __shared__ float fin[NHID * NLAY];
    __shared__ float cpart[2][64];

    const float* QK = QKm + (size_t)h * NN * 256;
    const float* T = tmps + (size_t)(h + 1) * FSZ;
    const int n = cnts12[h * NN + row];
    const int* rc = cols12 + (size_t)(h * NN + row) * CAPA;
    const float* rv = vals12 + (size_t)(h * NN + row) * CAPA;

    for (int p = ht; p < n; p += 128) { cols[h][p] = rc[p]; avals[h][p] = rv[p]; }
    if (ht < 32) *reinterpret_cast<f32x4*>(&qrow[h][ht * 4]) =
        *reinterpret_cast<const f32x4*>(QK + (size_t)row * 256 + ht * 4);
    __syncthreads();

    const float W0 = watt[h * 2], W1 = watt[h * 2 + 1];

    if (n > 0) {
        int g = ht >> 5, sl = ht & 31;
        f32x4 qv = *reinterpret_cast<const f32x4*>(&qrow[h][sl * 4]);
        for (int p = g; p < n; p += 4) {
            f32x4 kv = *reinterpret_cast<const f32x4*>(QK + (size_t)cols[h][p] * 256 + 128 + sl * 4);
            float s = qv[0] * kv[0] + qv[1] * kv[1] + qv[2] * kv[2] + qv[3] * kv[3];
            #pragma unroll
            for (int m = 16; m; m >>= 1) s += __shfl_xor(s, m);
            if (sl == 0) svals[h][p] = s;
        }
    }
    __syncthreads();

    if (n > 0 && ht < 64) {
        float mx = -3.0e38f;
        for (int p = ht; p < n; p += 64) mx = fmaxf(mx, svals[h][p]);
        #pragma unroll
        for (int m = 32; m; m >>= 1) mx = fmaxf(mx, __shfl_xor(mx, m));
        float ss = 0.f;
        for (int p = ht; p < n; p += 64) ss += expf(svals[h][p] - mx);
        #pragma unroll
        for (int m = 32; m; m >>= 1) ss += __shfl_xor(ss, m);
        float inv = 1.0f / ss;
        for (int p = ht; p < n; p += 64) avals[h][p] = expf(svals[h][p] - mx) * inv * W0 + avals[h][p] * W1;
    }
    __syncthreads();

    float acc = 0.f;
    if (n > 0) {
        float a1 = 0.f;
        int p = 0;
        for (; p + 2 <= n; p += 2) {
            acc = fmaf(avals[h][p],     T[(size_t)cols[h][p]     * NHID + ht], acc);
            a1  = fmaf(avals[h][p + 1], T[(size_t)cols[h][p + 1] * NHID + ht], a1);
        }
        if (p < n) acc = fmaf(avals[h][p], T[(size_t)cols[h][p] * NHID + ht], acc);
        acc += a1;
    } else {
        acc = W0 * (1.0f / (float)NN) * colsum[h * NHID + ht];
    }

    float s2 = acc * acc;
    #pragma unroll
    for (int m = 32; m; m >>= 1) s2 += __shfl_xor(s2, m);
    if ((t & 63) == 0) ws[t >> 6] = s2;

    float v0 = 0.f;
    if (t < 128) {
        v0 = tmps[(size_t)row * NHID + t];
        float s0 = v0 * v0;
        #pragma unroll
        for (int m = 32; m; m >>= 1) s0 += __shfl_xor(s0, m);
        if ((t & 63) == 0) ws0[t >> 6] = s0;
    }
    __syncthreads();

    {
        float d = fmaxf(sqrtf(ws[h * 2] + ws[h * 2 + 1]), 1e-12f);
        fin[(h + 1) * NHID + ht] = fmaxf(mask[h + 1] * acc / d, 0.f);
        if (t < 128) {
            float d0 = fmaxf(sqrtf(ws0[0] + ws0[1]), 1e-12f);
            fin[t] = fmaxf(mask[0] * v0 / d0, 0.f);
        }
    }
    __syncthreads();

    const int wv = t >> 6, lane = t & 63;
    if (wv < 2 && lane < NCLASS) {
        const float* wrow = Wc + (size_t)lane * (NHID * NLAY) + wv * 192;
        const float* fi = fin + wv * 192;
        float a0 = 0.f, a1 = 0.f, a2 = 0.f, a3 = 0.f;
        #pragma unroll 4
        for (int k = 0; k < 192; k += 4) {
            a0 = fmaf(fi[k],     wrow[k],     a0);
            a1 = fmaf(fi[k + 1], wrow[k + 1], a1);
            a2 = fmaf(fi[k + 2], wrow[k + 2], a2);
            a3 = fmaf(fi[k + 3], wrow[k + 3], a3);
        }
        cpart[wv][lane] = (a0 + a1) + (a2 + a3);
    }
    __syncthreads();

    if (t < 64) {
        float logit = (t < NCLASS) ? (cpart[0][t] + cpart[1][t] + bc[t]) : -3.0e38f;
        float mx = logit;
        #pragma unroll
        for (int m = 32; m; m >>= 1) mx = fmaxf(mx, __shfl_xor(mx, m));
        float e = (t < NCLASS) ? expf(logit - mx) : 0.f;
        float ssum = e;
        #pragma unroll
        for (int m = 32; m; m >>= 1) ssum += __shfl_xor(ssum, m);
        if (t < NCLASS) out[(size_t)row * NCLASS + t] = logit - mx - logf(ssum);
    }
}

// ================================================================ launch
extern "C" void kernel_launch(void* const* d_in, const int* in_sizes, int n_in,
                              void* d_out, int out_size, void* d_ws, size_t ws_size,
                              hipStream_t stream) {
    const float* x       = (const float*)d_in[0];
    const float* adj1    = (const float*)d_in[1];
    const float* adj2    = (const float*)d_in[2];
    const float* adj_att = (const float*)d_in[3];
    const float* fc1_w   = (const float*)d_in[4];
    const float* fc1_b   = (const float*)d_in[5];
    const float* Q_w     = (const float*)d_in[6];
    const float* Q_b     = (const float*)d_in[7];
    const float* K_w     = (const float*)d_in[8];
    const float* K_b     = (const float*)d_in[9];
    const float* hop     = (const float*)d_in[10];
    const float* w       = (const float*)d_in[11];
    const float* clf_w   = (const float*)d_in[12];
    const float* clf_b   = (const float*)d_in[13];

    float* W = (float*)d_ws;
    float* f_mask   = W;                   // 4
    float* f_watt   = W + 4;               // 4
    float* f_colsum = W + 8;               // 256
    float* rowsumA  = W + 264;             // NN
    float* tmps     = W + 264 + NN;        // 3F
    float* tmp_att  = tmps + 3 * FSZ;      // 2F
    float* QKm      = tmp_att + 2 * FSZ;   // 4F (2 layers x [NN,256])
    float* csr_valsA = QKm + 4 * FSZ;      // F   (adj_att)
    float* csr_vals12 = csr_valsA + FSZ;   // 2F  (adj1, adj2)
    int*   csr_colsA = (int*)(csr_vals12 + 2 * FSZ); // F ints
    int*   csr_cols12 = csr_colsA + FSZ;             // 2F ints
    int*   csr_cntA  = csr_cols12 + 2 * FSZ;         // NN ints
    int*   csr_cnt12 = csr_cntA + NN;                // 2*NN ints

    size_t need = (size_t)((char*)(csr_cnt12 + 2 * NN) - (char*)d_ws);
    if (ws_size < need) return;

    // D1: fc1 GEMM + adj_att scan + setup
    k_d1<<<384 + NN + 1, 256, 0, stream>>>(
        x, fc1_w, fc1_b, adj_att, hop, w,
        tmps, f_mask, f_watt, f_colsum, rowsumA, csr_cntA, csr_colsA, csr_valsA);

    // D2: spmm1 (both layers per block) + colsum + adj1 scan co-resident
    k_d2<<<NN + 64 + NN, 256, 0, stream>>>(
        csr_cntA, csr_colsA, csr_valsA, tmps, tmp_att, f_colsum,
        adj1, csr_cnt12, csr_cols12, csr_vals12);

    // D3: T2 gather + QKm GEMM + adj2 scan co-resident
    k_d3<<<256 + NN, 256, 0, stream>>>(
        csr_cntA, csr_colsA, csr_valsA, tmp_att, Q_w, K_w, Q_b, K_b, rowsumA, QKm,
        adj2, csr_cnt12, csr_cols12, csr_vals12);

    // D4: attention (both layers) + layer-0 norm + classifier + log_softmax
    k_attn_clf<<<NN, 256, 0, stream>>>(
        csr_cnt12, csr_cols12, csr_vals12, QKm, tmps, f_colsum, f_watt, f_mask,
        clf_w, clf_b, (float*)d_out);
}

// Round 11
// 366.134 us; speedup vs baseline: 1.1374x; 1.1374x over previous
//
#include <hip/hip_runtime.h>
#include <hip/hip_bf16.h>

#define NN     8192
#define NFEAT  512
#define NHID   128
#define NCLASS 40
#define NLAY   3
#define CAPA   128           // CSR capacity/row (nnz ~ Binomial(8192,0.002), mean 16.4)
#define FSZ    ((size_t)NN * NHID)

typedef float f32x4 __attribute__((ext_vector_type(4)));

// ================================================================ D1: fc1 + adjA scan + setup
// grid (384 + NN + 1). bx<384: fc1 tile. 384<=bx<384+NN: scan adjA row (batched v[8]). last: setup.
// lb(256,4): fc1 = 48 VGPR (R7 measured), scan v[8] fits without spill.
__global__ __launch_bounds__(256, 4) void k_d1(
    const float* __restrict__ x, const float* __restrict__ fc1w, const float* __restrict__ fc1b,
    const float* __restrict__ adjA, const float* __restrict__ hop, const float* __restrict__ w,
    float* __restrict__ tmps, float* __restrict__ f_mask, float* __restrict__ f_watt,
    float* __restrict__ colsum, float* __restrict__ rowsumA,
    int* __restrict__ cntsA, int* __restrict__ colsA, float* __restrict__ valsA)
{
    __shared__ float smem[3200];       // fc1: As[16][68] | Bs[16][132]; scan: [0]=lcnt [1]=lsum
    const int bx = blockIdx.x, tid = threadIdx.x;

    if (bx < 384) {
        // ---------------- fc1 tile: BM=64, BN=128, BK=16 ----------------
        float* As = smem;              // [16][68]
        float* Bs = smem + 1088;       // [16][132]
        const int tx = tid & 15, ty = tid >> 4;
        const int bm = (bx & 127) * 64;
        const int layer = bx >> 7;
        const int bn = layer * 128;
        float acc[4][8] = {};

        const int rA = tid >> 2, cA = (tid & 3) * 4;
        for (int kt = 0; kt < NFEAT; kt += 16) {
            f32x4 va = *reinterpret_cast<const f32x4*>(&x[(size_t)(bm + rA) * NFEAT + kt + cA]);
            As[(cA + 0) * 68 + rA] = va[0];
            As[(cA + 1) * 68 + rA] = va[1];
            As[(cA + 2) * 68 + rA] = va[2];
            As[(cA + 3) * 68 + rA] = va[3];
            #pragma unroll
            for (int it = 0; it < 2; ++it) {
                int L = tid + it * 256;
                int r = L >> 2, c4 = (L & 3) * 4;
                f32x4 vb = *reinterpret_cast<const f32x4*>(&fc1w[(size_t)(bn + r) * NFEAT + kt + c4]);
                Bs[(c4 + 0) * 132 + r] = vb[0];
                Bs[(c4 + 1) * 132 + r] = vb[1];
                Bs[(c4 + 2) * 132 + r] = vb[2];
                Bs[(c4 + 3) * 132 + r] = vb[3];
            }
            __syncthreads();
            #pragma unroll
            for (int kk = 0; kk < 16; ++kk) {
                f32x4 ra  = *reinterpret_cast<const f32x4*>(&As[kk * 68 + ty * 4]);
                f32x4 rb0 = *reinterpret_cast<const f32x4*>(&Bs[kk * 132 + tx * 4]);
                f32x4 rb1 = *reinterpret_cast<const f32x4*>(&Bs[kk * 132 + tx * 4 + 64]);
                #pragma unroll
                for (int i = 0; i < 4; ++i) {
                    #pragma unroll
                    for (int j = 0; j < 4; ++j) {
                        acc[i][j]     = fmaf(ra[i], rb0[j], acc[i][j]);
                        acc[i][j + 4] = fmaf(ra[i], rb1[j], acc[i][j + 4]);
                    }
                }
            }
            __syncthreads();
        }
        const float* bofs = fc1b + bn;
        #pragma unroll
        for (int i = 0; i < 4; ++i) {
            int m = bm + ty * 4 + i;
            #pragma unroll
            for (int j = 0; j < 8; ++j) {
                int lc = (j < 4) ? (tx * 4 + j) : (64 + tx * 4 + (j - 4));
                tmps[(size_t)layer * FSZ + (size_t)m * NHID + lc] = acc[i][j] + bofs[lc];
            }
        }
    } else if (bx < 384 + NN) {
        // ---------------- adjA scan (one row, batched loads) ----------------
        const int row = bx - 384;
        int* s_lcnt = (int*)smem;
        float* s_lsum = smem + 1;
        if (tid == 0) { *s_lcnt = 0; *s_lsum = 0.f; }
        __syncthreads();
        const f32x4* arow = reinterpret_cast<const f32x4*>(adjA + (size_t)row * NN);
        int* rc = colsA + (size_t)row * CAPA;
        float* rv = valsA + (size_t)row * CAPA;

        f32x4 v[8];
        #pragma unroll
        for (int i = 0; i < 8; ++i) v[i] = arow[tid + (i << 8)];

        float ls = 0.f;
        #pragma unroll
        for (int i = 0; i < 8; ++i) {
            const int c4 = tid + (i << 8);
            #pragma unroll
            for (int k = 0; k < 4; ++k) {
                if (v[i][k] > 0.f) {
                    int p = atomicAdd(s_lcnt, 1);
                    if (p < CAPA) { rc[p] = c4 * 4 + k; rv[p] = v[i][k]; }
                    ls += v[i][k];
                }
            }
        }
        if (ls != 0.f) atomicAdd(s_lsum, ls);
        __syncthreads();
        if (tid == 0) {
            int n = *s_lcnt;
            cntsA[row] = n < CAPA ? n : CAPA;
            rowsumA[row] = *s_lsum;
        }
    } else {
        // ---------------- setup ----------------
        colsum[tid] = 0.f;             // 256 entries (2 layers x 128)
        if (tid == 0) {
            float m = fmaxf(fmaxf(hop[0], hop[1]), hop[2]);
            float e0 = expf(hop[0] - m), e1 = expf(hop[1] - m), e2 = expf(hop[2] - m);
            float s = e0 + e1 + e2;
            f_mask[0] = e0 / s; f_mask[1] = e1 / s; f_mask[2] = e2 / s;
            for (int l = 0; l < 2; ++l) {
                float a = w[2 * l], b = w[2 * l + 1];
                float mm = fmaxf(a, b);
                float ea = expf(a - mm), eb = expf(b - mm);
                float ss = ea + eb;
                f_watt[2 * l] = ea / ss; f_watt[2 * l + 1] = eb / ss;
            }
        }
    }
}

// ================================================================ D2: spmm1 (both layers) + colsum + adj1 scan
// grid (NN + 64 + NN). bx<NN: spmm row (both layers, 256 thr). bx<NN+64: colsum chunk. else: scan adj1 row.
__global__ __launch_bounds__(256, 4) void k_d2(
    const int* __restrict__ cntsA, const int* __restrict__ colsA, const float* __restrict__ valsA,
    const float* __restrict__ tmps, float* __restrict__ tmp_att, float* __restrict__ colsum,
    const float* __restrict__ adj1,
    int* __restrict__ cnts12, int* __restrict__ cols12, float* __restrict__ vals12)
{
    __shared__ int sc[CAPA];
    __shared__ float sv[CAPA];
    __shared__ int s_lcnt;
    const int bx = blockIdx.x, t = threadIdx.x;

    if (bx < NN) {
        // ---------------- spmm both layers of row bx ----------------
        const int row = bx;
        const int n = cntsA[row];
        for (int p = t; p < n; p += 256) { sc[p] = colsA[(size_t)row * CAPA + p]; sv[p] = valsA[(size_t)row * CAPA + p]; }
        __syncthreads();
        const int h = t >> 7, col = t & 127;
        const float* X = tmps + (size_t)(h + 1) * FSZ;
        float a0 = 0.f, a1 = 0.f, a2 = 0.f, a3 = 0.f;
        int p = 0;
        for (; p + 4 <= n; p += 4) {
            a0 = fmaf(sv[p],     X[(size_t)sc[p]     * NHID + col], a0);
            a1 = fmaf(sv[p + 1], X[(size_t)sc[p + 1] * NHID + col], a1);
            a2 = fmaf(sv[p + 2], X[(size_t)sc[p + 2] * NHID + col], a2);
            a3 = fmaf(sv[p + 3], X[(size_t)sc[p + 3] * NHID + col], a3);
        }
        for (; p < n; ++p) a0 = fmaf(sv[p], X[(size_t)sc[p] * NHID + col], a0);
        tmp_att[(size_t)h * FSZ + (size_t)row * NHID + col] = (a0 + a1) + (a2 + a3);
    } else if (bx < NN + 64) {
        // ---------------- colsum chunk ----------------
        const int c = bx - NN;
        const int h = t >> 7, col = t & 127;
        const float* X = tmps + (size_t)(h + 1) * FSZ + (size_t)c * 128 * NHID;
        float a = 0.f;
        for (int r = 0; r < 128; ++r) a += X[(size_t)r * NHID + col];
        atomicAdd(&colsum[h * NHID + col], a);
    } else {
        // ---------------- adj1 scan (mat 0) ----------------
        const int row = bx - NN - 64;
        if (t == 0) s_lcnt = 0;
        __syncthreads();
        const f32x4* arow = reinterpret_cast<const f32x4*>(adj1 + (size_t)row * NN);
        int* rc = cols12 + (size_t)row * CAPA;
        float* rv = vals12 + (size_t)row * CAPA;

        f32x4 v[8];
        #pragma unroll
        for (int i = 0; i < 8; ++i) v[i] = arow[t + (i << 8)];

        #pragma unroll
        for (int i = 0; i < 8; ++i) {
            const int c4 = t + (i << 8);
            #pragma unroll
            for (int k = 0; k < 4; ++k) {
                if (v[i][k] > 0.f) {
                    int p = atomicAdd(&s_lcnt, 1);
                    if (p < CAPA) { rc[p] = c4 * 4 + k; rv[p] = v[i][k]; }
                }
            }
        }
        __syncthreads();
        if (t == 0) cnts12[row] = s_lcnt < CAPA ? s_lcnt : CAPA;
    }
}

// ================================================================ D3: t2qkm + adj2 scan
// grid (256 + NN). b<256: T2 gather + QKm GEMM. else: scan adj2 row (mat 1).
__global__ __launch_bounds__(256, 4) void k_d3(
    const int* __restrict__ cntsA, const int* __restrict__ colsA, const float* __restrict__ valsA,
    const float* __restrict__ tmp_att, const float* __restrict__ Qw, const float* __restrict__ Kw,
    const float* __restrict__ Qb, const float* __restrict__ Kb,
    const float* __restrict__ rowsumA, float* __restrict__ QKm,
    const float* __restrict__ adj2,
    int* __restrict__ cnts12, int* __restrict__ cols12, float* __restrict__ vals12)
{
    __shared__ float AsT[8192];        // t2: [k=128][row=64]; scan: [0]=lcnt
    const int b = blockIdx.x, tid = threadIdx.x;

    if (b < 256) {
        // ---------------- T2 gather + QKm GEMM ----------------
        const int bm = (b & 127) * 64, Lz = b >> 7;
        const float* X = tmp_att + (size_t)Lz * FSZ;
        {
            const int lrow = tid >> 2, coff = (tid & 3) * 32;
            const int row = bm + lrow;
            f32x4 acc[8] = {};
            const int n = cntsA[row];
            const int* rc = colsA + (size_t)row * CAPA;
            const float* rv = valsA + (size_t)row * CAPA;
            for (int p = 0; p < n; ++p) {
                int c = rc[p];
                float v = rv[p];
                const f32x4* src = reinterpret_cast<const f32x4*>(X + (size_t)c * NHID + coff);
                #pragma unroll
                for (int j = 0; j < 8; ++j) {
                    f32x4 s = src[j];
                    acc[j][0] = fmaf(v, s[0], acc[j][0]);
                    acc[j][1] = fmaf(v, s[1], acc[j][1]);
                    acc[j][2] = fmaf(v, s[2], acc[j][2]);
                    acc[j][3] = fmaf(v, s[3], acc[j][3]);
                }
            }
            #pragma unroll
            for (int j = 0; j < 8; ++j)
                #pragma unroll
                for (int q = 0; q < 4; ++q)
                    AsT[(coff + j * 4 + q) * 64 + lrow] = acc[j][q];
        }
        __syncthreads();

        const int tx = tid & 15, ty = tid >> 4;
        float rs[4];
        #pragma unroll
        for (int i = 0; i < 4; ++i) rs[i] = rowsumA[bm + ty * 4 + i];
        float* C = QKm + (size_t)Lz * NN * 256;

        #pragma unroll
        for (int ch = 0; ch < 4; ++ch) {
            const int bn = ch * 64;
            const float* Bp; const float* bp; int bc;
            if (bn < 128) { Bp = Qw + (size_t)Lz * NHID * NHID; bp = Qb + (size_t)Lz * NHID; bc = bn; }
            else          { Bp = Kw + (size_t)Lz * NHID * NHID; bp = Kb + (size_t)Lz * NHID; bc = bn - 128; }
            float acc[4][4] = {};
            for (int k4 = 0; k4 < NHID; k4 += 4) {
                f32x4 wv[4];
                #pragma unroll
                for (int j = 0; j < 4; ++j)
                    wv[j] = *reinterpret_cast<const f32x4*>(&Bp[(size_t)(bc + tx * 4 + j) * NHID + k4]);
                #pragma unroll
                for (int q = 0; q < 4; ++q) {
                    f32x4 ra = *reinterpret_cast<const f32x4*>(&AsT[(k4 + q) * 64 + ty * 4]);
                    #pragma unroll
                    for (int i = 0; i < 4; ++i)
                        #pragma unroll
                        for (int j = 0; j < 4; ++j)
                            acc[i][j] = fmaf(ra[i], wv[j][q], acc[i][j]);
                }
            }
            #pragma unroll
            for (int i = 0; i < 4; ++i) {
                int m = bm + ty * 4 + i;
                #pragma unroll
                for (int j = 0; j < 4; ++j) {
                    int nc = bn + tx * 4 + j;
                    C[(size_t)m * 256 + nc] = acc[i][j] + rs[i] * bp[bc + tx * 4 + j];
                }
            }
        }
    } else {
        // ---------------- adj2 scan (mat 1) ----------------
        const int row = b - 256;
        int* s_lcnt = (int*)AsT;
        if (tid == 0) *s_lcnt = 0;
        __syncthreads();
        const f32x4* arow = reinterpret_cast<const f32x4*>(adj2 + (size_t)row * NN);
        int* rc = cols12 + (size_t)(NN + row) * CAPA;
        float* rv = vals12 + (size_t)(NN + row) * CAPA;

        f32x4 v[8];
        #pragma unroll
        for (int i = 0; i < 8; ++i) v[i] = arow[tid + (i << 8)];

        #pragma unroll
        for (int i = 0; i < 8; ++i) {
            const int c4 = tid + (i << 8);
            #pragma unroll
            for (int k = 0; k < 4; ++k) {
                if (v[i][k] > 0.f) {
                    int p = atomicAdd(s_lcnt, 1);
                    if (p < CAPA) { rc[p] = c4 * 4 + k; rv[p] = v[i][k]; }
                }
            }
        }
        __syncthreads();
        if (tid == 0) cnts12[NN + row] = *s_lcnt < CAPA ? *s_lcnt : CAPA;
    }
}

// ================================================================ D4: attention (both layers) + clf
__global__ __launch_bounds__(256) void k_attn_clf(
    const int* __restrict__ cnts12, const int* __restrict__ cols12, const float* __restrict__ vals12,
    const float* __restrict__ QKm, const float* __restrict__ tmps,
    const float* __restrict__ colsum, const float* __restrict__ watt,
    const float* __restrict__ mask, const float* __restrict__ Wc, const float* __restrict__ bc,
    float* __restrict__ out)
{
    const int row = blockIdx.x, t = threadIdx.x;
    const int h = t >> 7, ht = t & 127;          // half h: layer h+1
    __shared__ int cols[2][CAPA];
    __shared__ float avals[2][CAPA];
    __shared__ float svals[2][CAPA];
    __shared__ __align__(16) float qrow[2][NHID];
    __shared__ float ws[4];
    __shared__ float ws0[2];
    __shared__ float fin[NHID * NLAY];
    __shared__ float cpart[2][64];

    const float* QK = QKm + (size_t)h * NN * 256;
    const float* T = tmps + (size_t)(h + 1) * FSZ;
    const int n = cnts12[h * NN + row];
    const int* rc = cols12 + (size_t)(h * NN + row) * CAPA;
    const float* rv = vals12 + (size_t)(h * NN + row) * CAPA;

    for (int p = ht; p < n; p += 128) { cols[h][p] = rc[p]; avals[h][p] = rv[p]; }
    if (ht < 32) *reinterpret_cast<f32x4*>(&qrow[h][ht * 4]) =
        *reinterpret_cast<const f32x4*>(QK + (size_t)row * 256 + ht * 4);
    __syncthreads();

    const float W0 = watt[h * 2], W1 = watt[h * 2 + 1];

    if (n > 0) {
        int g = ht >> 5, sl = ht & 31;
        f32x4 qv = *reinterpret_cast<const f32x4*>(&qrow[h][sl * 4]);
        for (int p = g; p < n; p += 4) {
            f32x4 kv = *reinterpret_cast<const f32x4*>(QK + (size_t)cols[h][p] * 256 + 128 + sl * 4);
            float s = qv[0] * kv[0] + qv[1] * kv[1] + qv[2] * kv[2] + qv[3] * kv[3];
            #pragma unroll
            for (int m = 16; m; m >>= 1) s += __shfl_xor(s, m);
            if (sl == 0) svals[h][p] = s;
        }
    }
    __syncthreads();

    if (n > 0 && ht < 64) {
        float mx = -3.0e38f;
        for (int p = ht; p < n; p += 64) mx = fmaxf(mx, svals[h][p]);
        #pragma unroll
        for (int m = 32; m; m >>= 1) mx = fmaxf(mx, __shfl_xor(mx, m));
        float ss = 0.f;
        for (int p = ht; p < n; p += 64) ss += expf(svals[h][p] - mx);
        #pragma unroll
        for (int m = 32; m; m >>= 1) ss += __shfl_xor(ss, m);
        float inv = 1.0f / ss;
        for (int p = ht; p < n; p += 64) avals[h][p] = expf(svals[h][p] - mx) * inv * W0 + avals[h][p] * W1;
    }
    __syncthreads();

    float acc = 0.f;
    if (n > 0) {
        float a1 = 0.f;
        int p = 0;
        for (; p + 2 <= n; p += 2) {
            acc = fmaf(avals[h][p],     T[(size_t)cols[h][p]     * NHID + ht], acc);
            a1  = fmaf(avals[h][p + 1], T[(size_t)cols[h][p + 1] * NHID + ht], a1);
        }
        if (p < n) acc = fmaf(avals[h][p], T[(size_t)cols[h][p] * NHID + ht], acc);
        acc += a1;
    } else {
        acc = W0 * (1.0f / (float)NN) * colsum[h * NHID + ht];
    }

    float s2 = acc * acc;
    #pragma unroll
    for (int m = 32; m; m >>= 1) s2 += __shfl_xor(s2, m);
    if ((t & 63) == 0) ws[t >> 6] = s2;

    float v0 = 0.f;
    if (t < 128) {
        v0 = tmps[(size_t)row * NHID + t];
        float s0 = v0 * v0;
        #pragma unroll
        for (int m = 32; m; m >>= 1) s0 += __shfl_xor(s0, m);
        if ((t & 63) == 0) ws0[t >> 6] = s0;
    }
    __syncthreads();

    {
        float d = fmaxf(sqrtf(ws[h * 2] + ws[h * 2 + 1]), 1e-12f);
        fin[(h + 1) * NHID + ht] = fmaxf(mask[h + 1] * acc / d, 0.f);
        if (t < 128) {
            float d0 = fmaxf(sqrtf(ws0[0] + ws0[1]), 1e-12f);
            fin[t] = fmaxf(mask[0] * v0 / d0, 0.f);
        }
    }
    __syncthreads();

    const int wv = t >> 6, lane = t & 63;
    if (wv < 2 && lane < NCLASS) {
        const float* wrow = Wc + (size_t)lane * (NHID * NLAY) + wv * 192;
        const float* fi = fin + wv * 192;
        float a0 = 0.f, a1 = 0.f, a2 = 0.f, a3 = 0.f;
        #pragma unroll 4
        for (int k = 0; k < 192; k += 4) {
            a0 = fmaf(fi[k],     wrow[k],     a0);
            a1 = fmaf(fi[k + 1], wrow[k + 1], a1);
            a2 = fmaf(fi[k + 2], wrow[k + 2], a2);
            a3 = fmaf(fi[k + 3], wrow[k + 3], a3);
        }
        cpart[wv][lane] = (a0 + a1) + (a2 + a3);
    }
    __syncthreads();

    if (t < 64) {
        float logit = (t < NCLASS) ? (cpart[0][t] + cpart[1][t] + bc[t]) : -3.0e38f;
        float mx = logit;
        #pragma unroll
        for (int m = 32; m; m >>= 1) mx = fmaxf(mx, __shfl_xor(mx, m));
        float e = (t < NCLASS) ? expf(logit - mx) : 0.f;
        float ssum = e;
        #pragma unroll
        for (int m = 32; m; m >>= 1) ssum += __shfl_xor(ssum, m);
        if (t < NCLASS) out[(size_t)row * NCLASS + t] = logit - mx - logf(ssum);
    }
}

// ================================================================ launch
extern "C" void kernel_launch(void* const* d_in, const int* in_sizes, int n_in,
                              void* d_out, int out_size, void* d_ws, size_t ws_size,
                              hipStream_t stream) {
    const float* x       = (const float*)d_in[0];
    const float* adj1    = (const float*)d_in[1];
    const float* adj2    = (const float*)d_in[2];
    const float* adj_att = (const float*)d_in[3];
    const float* fc1_w   = (const float*)d_in[4];
    const float* fc1_b   = (const float*)d_in[5];
    const float* Q_w     = (const float*)d_in[6];
    const float* Q_b     = (const float*)d_in[7];
    const float* K_w     = (const float*)d_in[8];
    const float* K_b     = (const float*)d_in[9];
    const float* hop     = (const float*)d_in[10];
    const float* w       = (const float*)d_in[11];
    const float* clf_w   = (const float*)d_in[12];
    const float* clf_b   = (const float*)d_in[13];

    float* W = (float*)d_ws;
    float* f_mask   = W;                   // 4
    float* f_watt   = W + 4;               // 4
    float* f_colsum = W + 8;               // 256
    float* rowsumA  = W + 264;             // NN
    float* tmps     = W + 264 + NN;        // 3F
    float* tmp_att  = tmps + 3 * FSZ;      // 2F
    float* QKm      = tmp_att + 2 * FSZ;   // 4F (2 layers x [NN,256])
    float* csr_valsA = QKm + 4 * FSZ;      // F   (adj_att)
    float* csr_vals12 = csr_valsA + FSZ;   // 2F  (adj1, adj2)
    int*   csr_colsA = (int*)(csr_vals12 + 2 * FSZ); // F ints
    int*   csr_cols12 = csr_colsA + FSZ;             // 2F ints
    int*   csr_cntA  = csr_cols12 + 2 * FSZ;         // NN ints
    int*   csr_cnt12 = csr_cntA + NN;                // 2*NN ints

    size_t need = (size_t)((char*)(csr_cnt12 + 2 * NN) - (char*)d_ws);
    if (ws_size < need) return;

    // D1: fc1 GEMM + adj_att scan + setup
    k_d1<<<384 + NN + 1, 256, 0, stream>>>(
        x, fc1_w, fc1_b, adj_att, hop, w,
        tmps, f_mask, f_watt, f_colsum, rowsumA, csr_cntA, csr_colsA, csr_valsA);

    // D2: spmm1 (both layers per block) + colsum + adj1 scan co-resident
    k_d2<<<NN + 64 + NN, 256, 0, stream>>>(
        csr_cntA, csr_colsA, csr_valsA, tmps, tmp_att, f_colsum,
        adj1, csr_cnt12, csr_cols12, csr_vals12);

    // D3: T2 gather + QKm GEMM + adj2 scan co-resident
    k_d3<<<256 + NN, 256, 0, stream>>>(
        csr_cntA, csr_colsA, csr_valsA, tmp_att, Q_w, K_w, Q_b, K_b, rowsumA, QKm,
        adj2, csr_cnt12, csr_cols12, csr_vals12);

    // D4: attention (both layers) + layer-0 norm + classifier + log_softmax
    k_attn_clf<<<NN, 256, 0, stream>>>(
        csr_cnt12, csr_cols12, csr_vals12, QKm, tmps, f_colsum, f_watt, f_mask,
        clf_w, clf_b, (float*)d_out);
}

// Round 12
// 351.079 us; speedup vs baseline: 1.1862x; 1.0429x over previous
//
#include <hip/hip_runtime.h>
#include <hip/hip_bf16.h>

#define NN     8192
#define NFEAT  512
#define NHID   128
#define NCLASS 40
#define NLAY   3
#define CAPA   128           // CSR capacity/row (nnz ~ Binomial(8192,0.002), mean 16.4)
#define FSZ    ((size_t)NN * NHID)

typedef float f32x4 __attribute__((ext_vector_type(4)));

// ---------------------------------------------------------------- wave-parallel CSR extraction of one row
// One wave owns one row: 4 rounds of {8 batched f32x4 loads, ballot-compact}. No barriers, no LDS.
__device__ __forceinline__ void scan_row_wave(
    const float* __restrict__ adj, int row, int lane,
    int* __restrict__ rc, float* __restrict__ rv,
    int* __restrict__ cntOut, float* __restrict__ rowsumOut)
{
    const f32x4* arow = reinterpret_cast<const f32x4*>(adj + (size_t)row * NN);
    int base = 0;
    float ls = 0.f;
    #pragma unroll
    for (int r = 0; r < 4; ++r) {
        f32x4 v[8];
        #pragma unroll
        for (int i = 0; i < 8; ++i)
            v[i] = arow[(r * 8 + i) * 64 + lane];
        #pragma unroll
        for (int i = 0; i < 8; ++i) {
            const int c4 = ((r * 8 + i) * 64 + lane) * 4;
            #pragma unroll
            for (int k = 0; k < 4; ++k) {
                const bool has = v[i][k] > 0.f;
                const unsigned long long mask = __ballot(has);
                if (has) {
                    int p = base + (int)__popcll(mask & ((1ull << lane) - 1ull));
                    if (p < CAPA) { rc[p] = c4 + k; rv[p] = v[i][k]; }
                    ls += v[i][k];
                }
                base += (int)__popcll(mask);
            }
        }
    }
    if (rowsumOut) {
        #pragma unroll
        for (int m = 32; m; m >>= 1) ls += __shfl_xor(ls, m);
    }
    if (lane == 0) {
        *cntOut = base < CAPA ? base : CAPA;
        if (rowsumOut) *rowsumOut = ls;
    }
}

// ================================================================ D1: fc1 + adjA scan (wave-ballot) + setup
// grid (384 + NN/4 + 1). bx<384: fc1 tile. 384<=bx<384+2048: 4 rows of adjA (one per wave). last: setup.
__global__ __launch_bounds__(256, 4) void k_d1(
    const float* __restrict__ x, const float* __restrict__ fc1w, const float* __restrict__ fc1b,
    const float* __restrict__ adjA, const float* __restrict__ hop, const float* __restrict__ w,
    float* __restrict__ tmps, float* __restrict__ f_mask, float* __restrict__ f_watt,
    float* __restrict__ colsum, float* __restrict__ rowsumA,
    int* __restrict__ cntsA, int* __restrict__ colsA, float* __restrict__ valsA)
{
    __shared__ float smem[3200];       // fc1 only: As[16][68] | Bs[16][132]
    const int bx = blockIdx.x, tid = threadIdx.x;

    if (bx < 384) {
        // ---------------- fc1 tile: BM=64, BN=128, BK=16 ----------------
        float* As = smem;              // [16][68]
        float* Bs = smem + 1088;       // [16][132]
        const int tx = tid & 15, ty = tid >> 4;
        const int bm = (bx & 127) * 64;
        const int layer = bx >> 7;
        const int bn = layer * 128;
        float acc[4][8] = {};

        const int rA = tid >> 2, cA = (tid & 3) * 4;
        for (int kt = 0; kt < NFEAT; kt += 16) {
            f32x4 va = *reinterpret_cast<const f32x4*>(&x[(size_t)(bm + rA) * NFEAT + kt + cA]);
            As[(cA + 0) * 68 + rA] = va[0];
            As[(cA + 1) * 68 + rA] = va[1];
            As[(cA + 2) * 68 + rA] = va[2];
            As[(cA + 3) * 68 + rA] = va[3];
            #pragma unroll
            for (int it = 0; it < 2; ++it) {
                int L = tid + it * 256;
                int r = L >> 2, c4 = (L & 3) * 4;
                f32x4 vb = *reinterpret_cast<const f32x4*>(&fc1w[(size_t)(bn + r) * NFEAT + kt + c4]);
                Bs[(c4 + 0) * 132 + r] = vb[0];
                Bs[(c4 + 1) * 132 + r] = vb[1];
                Bs[(c4 + 2) * 132 + r] = vb[2];
                Bs[(c4 + 3) * 132 + r] = vb[3];
            }
            __syncthreads();
            #pragma unroll
            for (int kk = 0; kk < 16; ++kk) {
                f32x4 ra  = *reinterpret_cast<const f32x4*>(&As[kk * 68 + ty * 4]);
                f32x4 rb0 = *reinterpret_cast<const f32x4*>(&Bs[kk * 132 + tx * 4]);
                f32x4 rb1 = *reinterpret_cast<const f32x4*>(&Bs[kk * 132 + tx * 4 + 64]);
                #pragma unroll
                for (int i = 0; i < 4; ++i) {
                    #pragma unroll
                    for (int j = 0; j < 4; ++j) {
                        acc[i][j]     = fmaf(ra[i], rb0[j], acc[i][j]);
                        acc[i][j + 4] = fmaf(ra[i], rb1[j], acc[i][j + 4]);
                    }
                }
            }
            __syncthreads();
        }
        const float* bofs = fc1b + bn;
        #pragma unroll
        for (int i = 0; i < 4; ++i) {
            int m = bm + ty * 4 + i;
            #pragma unroll
            for (int j = 0; j < 8; ++j) {
                int lc = (j < 4) ? (tx * 4 + j) : (64 + tx * 4 + (j - 4));
                tmps[(size_t)layer * FSZ + (size_t)m * NHID + lc] = acc[i][j] + bofs[lc];
            }
        }
    } else if (bx < 384 + NN / 4) {
        // ---------------- adjA scan: one row per wave ----------------
        const int row = (bx - 384) * 4 + (tid >> 6);
        const int lane = tid & 63;
        scan_row_wave(adjA, row, lane,
                      colsA + (size_t)row * CAPA, valsA + (size_t)row * CAPA,
                      cntsA + row, rowsumA + row);
    } else {
        // ---------------- setup ----------------
        colsum[tid] = 0.f;             // 256 entries (2 layers x 128)
        if (tid == 0) {
            float m = fmaxf(fmaxf(hop[0], hop[1]), hop[2]);
            float e0 = expf(hop[0] - m), e1 = expf(hop[1] - m), e2 = expf(hop[2] - m);
            float s = e0 + e1 + e2;
            f_mask[0] = e0 / s; f_mask[1] = e1 / s; f_mask[2] = e2 / s;
            for (int l = 0; l < 2; ++l) {
                float a = w[2 * l], b = w[2 * l + 1];
                float mm = fmaxf(a, b);
                float ea = expf(a - mm), eb = expf(b - mm);
                float ss = ea + eb;
                f_watt[2 * l] = ea / ss; f_watt[2 * l + 1] = eb / ss;
            }
        }
    }
}

// ================================================================ D2: spmm1 (both layers) + colsum (R8 layout)
// grid (NN+64, 2): bx<NN -> tmp_att[y] = A_att @ tmps[y+1];  bx>=NN -> colsum 128-row chunk
__global__ __launch_bounds__(128) void k_spmm_cs(
    const int* __restrict__ cnts, const int* __restrict__ colsArr, const float* __restrict__ valsArr,
    const float* __restrict__ tmps, float* __restrict__ tmp_att, float* __restrict__ colsum)
{
    int bx = blockIdx.x, L = blockIdx.y, t = threadIdx.x;
    if (bx >= NN) {
        int c = bx - NN;
        const float* X = tmps + (size_t)(L + 1) * FSZ + (size_t)c * 128 * NHID;
        float a = 0.f;
        for (int r = 0; r < 128; ++r) a += X[(size_t)r * NHID + t];
        atomicAdd(&colsum[L * NHID + t], a);
        return;
    }
    int row = bx;
    const float* X = tmps + (size_t)(L + 1) * FSZ;
    float* Y = tmp_att + (size_t)L * FSZ;
    __shared__ int sc[CAPA];
    __shared__ float sv[CAPA];
    int n = cnts[row];
    for (int p = t; p < n; p += 128) { sc[p] = colsArr[(size_t)row * CAPA + p]; sv[p] = valsArr[(size_t)row * CAPA + p]; }
    __syncthreads();
    float a0 = 0.f, a1 = 0.f, a2 = 0.f, a3 = 0.f;
    int p = 0;
    for (; p + 4 <= n; p += 4) {
        a0 = fmaf(sv[p],     X[(size_t)sc[p]     * NHID + t], a0);
        a1 = fmaf(sv[p + 1], X[(size_t)sc[p + 1] * NHID + t], a1);
        a2 = fmaf(sv[p + 2], X[(size_t)sc[p + 2] * NHID + t], a2);
        a3 = fmaf(sv[p + 3], X[(size_t)sc[p + 3] * NHID + t], a3);
    }
    for (; p < n; ++p) a0 = fmaf(sv[p], X[(size_t)sc[p] * NHID + t], a0);
    Y[(size_t)row * NHID + t] = (a0 + a1) + (a2 + a3);
}

// ================================================================ D3: t2qkm + adj1/adj2 scan (wave-ballot)
// grid (256 + 2*NN/4). b<256: T2 gather + QKm GEMM. else: 4 rows of adj{1,2}, one per wave.
__global__ __launch_bounds__(256, 4) void k_d3(
    const int* __restrict__ cntsA, const int* __restrict__ colsA, const float* __restrict__ valsA,
    const float* __restrict__ tmp_att, const float* __restrict__ Qw, const float* __restrict__ Kw,
    const float* __restrict__ Qb, const float* __restrict__ Kb,
    const float* __restrict__ rowsumA, float* __restrict__ QKm,
    const float* __restrict__ adj1, const float* __restrict__ adj2,
    int* __restrict__ cnts12, int* __restrict__ cols12, float* __restrict__ vals12)
{
    __shared__ float AsT[8192];        // t2 only: [k=128][row=64]
    const int b = blockIdx.x, tid = threadIdx.x;

    if (b < 256) {
        // ---------------- T2 gather + QKm GEMM ----------------
        const int bm = (b & 127) * 64, Lz = b >> 7;
        const float* X = tmp_att + (size_t)Lz * FSZ;
        {
            const int lrow = tid >> 2, coff = (tid & 3) * 32;
            const int row = bm + lrow;
            f32x4 acc[8] = {};
            const int n = cntsA[row];
            const int* rc = colsA + (size_t)row * CAPA;
            const float* rv = valsA + (size_t)row * CAPA;
            for (int p = 0; p < n; ++p) {
                int c = rc[p];
                float v = rv[p];
                const f32x4* src = reinterpret_cast<const f32x4*>(X + (size_t)c * NHID + coff);
                #pragma unroll
                for (int j = 0; j < 8; ++j) {
                    f32x4 s = src[j];
                    acc[j][0] = fmaf(v, s[0], acc[j][0]);
                    acc[j][1] = fmaf(v, s[1], acc[j][1]);
                    acc[j][2] = fmaf(v, s[2], acc[j][2]);
                    acc[j][3] = fmaf(v, s[3], acc[j][3]);
                }
            }
            #pragma unroll
            for (int j = 0; j < 8; ++j)
                #pragma unroll
                for (int q = 0; q < 4; ++q)
                    AsT[(coff + j * 4 + q) * 64 + lrow] = acc[j][q];
        }
        __syncthreads();

        const int tx = tid & 15, ty = tid >> 4;
        float rs[4];
        #pragma unroll
        for (int i = 0; i < 4; ++i) rs[i] = rowsumA[bm + ty * 4 + i];
        float* C = QKm + (size_t)Lz * NN * 256;

        #pragma unroll
        for (int ch = 0; ch < 4; ++ch) {
            const int bn = ch * 64;
            const float* Bp; const float* bp; int bc;
            if (bn < 128) { Bp = Qw + (size_t)Lz * NHID * NHID; bp = Qb + (size_t)Lz * NHID; bc = bn; }
            else          { Bp = Kw + (size_t)Lz * NHID * NHID; bp = Kb + (size_t)Lz * NHID; bc = bn - 128; }
            float acc[4][4] = {};
            for (int k4 = 0; k4 < NHID; k4 += 4) {
                f32x4 wv[4];
                #pragma unroll
                for (int j = 0; j < 4; ++j)
                    wv[j] = *reinterpret_cast<const f32x4*>(&Bp[(size_t)(bc + tx * 4 + j) * NHID + k4]);
                #pragma unroll
                for (int q = 0; q < 4; ++q) {
                    f32x4 ra = *reinterpret_cast<const f32x4*>(&AsT[(k4 + q) * 64 + ty * 4]);
                    #pragma unroll
                    for (int i = 0; i < 4; ++i)
                        #pragma unroll
                        for (int j = 0; j < 4; ++j)
                            acc[i][j] = fmaf(ra[i], wv[j][q], acc[i][j]);
                }
            }
            #pragma unroll
            for (int i = 0; i < 4; ++i) {
                int m = bm + ty * 4 + i;
                #pragma unroll
                for (int j = 0; j < 4; ++j) {
                    int nc = bn + tx * 4 + j;
                    C[(size_t)m * 256 + nc] = acc[i][j] + rs[i] * bp[bc + tx * 4 + j];
                }
            }
        }
    } else {
        // ---------------- adj1/adj2 scan: one row per wave ----------------
        const int e = (b - 256) * 4 + (tid >> 6);     // 0..16383
        const int mat = e >> 13, row = e & (NN - 1);  // 0->adj1, 1->adj2
        const int lane = tid & 63;
        const float* adj = mat ? adj2 : adj1;
        scan_row_wave(adj, row, lane,
                      cols12 + (size_t)(mat * NN + row) * CAPA,
                      vals12 + (size_t)(mat * NN + row) * CAPA,
                      cnts12 + mat * NN + row, nullptr);
    }
}

// ================================================================ D4: attention (both layers) + clf (R8 layout)
__global__ __launch_bounds__(256) void k_attn_clf(
    const int* __restrict__ cnts12, const int* __restrict__ cols12, const float* __restrict__ vals12,
    const float* __restrict__ QKm, const float* __restrict__ tmps,
    const float* __restrict__ colsum, const float* __restrict__ watt,
    const float* __restrict__ mask, const float* __restrict__ Wc, const float* __restrict__ bc,
    float* __restrict__ out)
{
    const int row = blockIdx.x, t = threadIdx.x;
    const int h = t >> 7, ht = t & 127;          // half h: layer h+1
    __shared__ int cols[2][CAPA];
    __shared__ float avals[2][CAPA];
    __shared__ float svals[2][CAPA];
    __shared__ __align__(16) float qrow[2][NHID];
    __shared__ float ws[4];
    __shared__ float ws0[2];
    __shared__ float fin[NHID * NLAY];
    __shared__ float cpart[2][64];

    const float* QK = QKm + (size_t)h * NN * 256;
    const float* T = tmps + (size_t)(h + 1) * FSZ;
    const int n = cnts12[h * NN + row];
    const int* rc = cols12 + (size_t)(h * NN + row) * CAPA;
    const float* rv = vals12 + (size_t)(h * NN + row) * CAPA;

    for (int p = ht; p < n; p += 128) { cols[h][p] = rc[p]; avals[h][p] = rv[p]; }
    if (ht < 32) *reinterpret_cast<f32x4*>(&qrow[h][ht * 4]) =
        *reinterpret_cast<const f32x4*>(QK + (size_t)row * 256 + ht * 4);
    __syncthreads();

    const float W0 = watt[h * 2], W1 = watt[h * 2 + 1];

    if (n > 0) {
        int g = ht >> 5, sl = ht & 31;
        f32x4 qv = *reinterpret_cast<const f32x4*>(&qrow[h][sl * 4]);
        for (int p = g; p < n; p += 4) {
            f32x4 kv = *reinterpret_cast<const f32x4*>(QK + (size_t)cols[h][p] * 256 + 128 + sl * 4);
            float s = qv[0] * kv[0] + qv[1] * kv[1] + qv[2] * kv[2] + qv[3] * kv[3];
            #pragma unroll
            for (int m = 16; m; m >>= 1) s += __shfl_xor(s, m);
            if (sl == 0) svals[h][p] = s;
        }
    }
    __syncthreads();

    if (n > 0 && ht < 64) {
        float mx = -3.0e38f;
        for (int p = ht; p < n; p += 64) mx = fmaxf(mx, svals[h][p]);
        #pragma unroll
        for (int m = 32; m; m >>= 1) mx = fmaxf(mx, __shfl_xor(mx, m));
        float ss = 0.f;
        for (int p = ht; p < n; p += 64) ss += expf(svals[h][p] - mx);
        #pragma unroll
        for (int m = 32; m; m >>= 1) ss += __shfl_xor(ss, m);
        float inv = 1.0f / ss;
        for (int p = ht; p < n; p += 64) avals[h][p] = expf(svals[h][p] - mx) * inv * W0 + avals[h][p] * W1;
    }
    __syncthreads();

    float acc = 0.f;
    if (n > 0) {
        float a1 = 0.f;
        int p = 0;
        for (; p + 2 <= n; p += 2) {
            acc = fmaf(avals[h][p],     T[(size_t)cols[h][p]     * NHID + ht], acc);
            a1  = fmaf(avals[h][p + 1], T[(size_t)cols[h][p + 1] * NHID + ht], a1);
        }
        if (p < n) acc = fmaf(avals[h][p], T[(size_t)cols[h][p] * NHID + ht], acc);
        acc += a1;
    } else {
        acc = W0 * (1.0f / (float)NN) * colsum[h * NHID + ht];
    }

    float s2 = acc * acc;
    #pragma unroll
    for (int m = 32; m; m >>= 1) s2 += __shfl_xor(s2, m);
    if ((t & 63) == 0) ws[t >> 6] = s2;

    float v0 = 0.f;
    if (t < 128) {
        v0 = tmps[(size_t)row * NHID + t];
        float s0 = v0 * v0;
        #pragma unroll
        for (int m = 32; m; m >>= 1) s0 += __shfl_xor(s0, m);
        if ((t & 63) == 0) ws0[t >> 6] = s0;
    }
    __syncthreads();

    {
        float d = fmaxf(sqrtf(ws[h * 2] + ws[h * 2 + 1]), 1e-12f);
        fin[(h + 1) * NHID + ht] = fmaxf(mask[h + 1] * acc / d, 0.f);
        if (t < 128) {
            float d0 = fmaxf(sqrtf(ws0[0] + ws0[1]), 1e-12f);
            fin[t] = fmaxf(mask[0] * v0 / d0, 0.f);
        }
    }
    __syncthreads();

    const int wv = t >> 6, lane = t & 63;
    if (wv < 2 && lane < NCLASS) {
        const float* wrow = Wc + (size_t)lane * (NHID * NLAY) + wv * 192;
        const float* fi = fin + wv * 192;
        float a0 = 0.f, a1 = 0.f, a2 = 0.f, a3 = 0.f;
        #pragma unroll 4
        for (int k = 0; k < 192; k += 4) {
            a0 = fmaf(fi[k],     wrow[k],     a0);
            a1 = fmaf(fi[k + 1], wrow[k + 1], a1);
            a2 = fmaf(fi[k + 2], wrow[k + 2], a2);
            a3 = fmaf(fi[k + 3], wrow[k + 3], a3);
        }
        cpart[wv][lane] = (a0 + a1) + (a2 + a3);
    }
    __syncthreads();

    if (t < 64) {
        float logit = (t < NCLASS) ? (cpart[0][t] + cpart[1][t] + bc[t]) : -3.0e38f;
        float mx = logit;
        #pragma unroll
        for (int m = 32; m; m >>= 1) mx = fmaxf(mx, __shfl_xor(mx, m));
        float e = (t < NCLASS) ? expf(logit - mx) : 0.f;
        float ssum = e;
        #pragma unroll
        for (int m = 32; m; m >>= 1) ssum += __shfl_xor(ssum, m);
        if (t < NCLASS) out[(size_t)row * NCLASS + t] = logit - mx - logf(ssum);
    }
}

// ================================================================ launch
extern "C" void kernel_launch(void* const* d_in, const int* in_sizes, int n_in,
                              void* d_out, int out_size, void* d_ws, size_t ws_size,
                              hipStream_t stream) {
    const float* x       = (const float*)d_in[0];
    const float* adj1    = (const float*)d_in[1];
    const float* adj2    = (const float*)d_in[2];
    const float* adj_att = (const float*)d_in[3];
    const float* fc1_w   = (const float*)d_in[4];
    const float* fc1_b   = (const float*)d_in[5];
    const float* Q_w     = (const float*)d_in[6];
    const float* Q_b     = (const float*)d_in[7];
    const float* K_w     = (const float*)d_in[8];
    const float* K_b     = (const float*)d_in[9];
    const float* hop     = (const float*)d_in[10];
    const float* w       = (const float*)d_in[11];
    const float* clf_w   = (const float*)d_in[12];
    const float* clf_b   = (const float*)d_in[13];

    float* W = (float*)d_ws;
    float* f_mask   = W;                   // 4
    float* f_watt   = W + 4;               // 4
    float* f_colsum = W + 8;               // 256
    float* rowsumA  = W + 264;             // NN
    float* tmps     = W + 264 + NN;        // 3F
    float* tmp_att  = tmps + 3 * FSZ;      // 2F
    float* QKm      = tmp_att + 2 * FSZ;   // 4F (2 layers x [NN,256])
    float* csr_valsA = QKm + 4 * FSZ;      // F   (adj_att)
    float* csr_vals12 = csr_valsA + FSZ;   // 2F  (adj1, adj2)
    int*   csr_colsA = (int*)(csr_vals12 + 2 * FSZ); // F ints
    int*   csr_cols12 = csr_colsA + FSZ;             // 2F ints
    int*   csr_cntA  = csr_cols12 + 2 * FSZ;         // NN ints
    int*   csr_cnt12 = csr_cntA + NN;                // 2*NN ints

    size_t need = (size_t)((char*)(csr_cnt12 + 2 * NN) - (char*)d_ws);
    if (ws_size < need) return;

    // D1: fc1 GEMM + adj_att wave-ballot scan + setup
    k_d1<<<384 + NN / 4 + 1, 256, 0, stream>>>(
        x, fc1_w, fc1_b, adj_att, hop, w,
        tmps, f_mask, f_watt, f_colsum, rowsumA, csr_cntA, csr_colsA, csr_valsA);

    // D2: tmp_att[L] = A_att @ tmps[L+1] + colsum
    k_spmm_cs<<<dim3(NN + 64, 2), 128, 0, stream>>>(
        csr_cntA, csr_colsA, csr_valsA, tmps, tmp_att, f_colsum);

    // D3: T2 gather + QKm GEMM + adj1/adj2 wave-ballot scans
    k_d3<<<256 + 2 * NN / 4, 256, 0, stream>>>(
        csr_cntA, csr_colsA, csr_valsA, tmp_att, Q_w, K_w, Q_b, K_b, rowsumA, QKm,
        adj1, adj2, csr_cnt12, csr_cols12, csr_vals12);

    // D4: attention (both layers) + layer-0 norm + classifier + log_softmax
    k_attn_clf<<<NN, 256, 0, stream>>>(
        csr_cnt12, csr_cols12, csr_vals12, QKm, tmps, f_colsum, f_watt, f_mask,
        clf_w, clf_b, (float*)d_out);
}